// Round 4
// baseline (1403.039 us; speedup 1.0000x reference)
//
#include <hip/hip_runtime.h>
#include <math.h>

#define D_MODEL 1024
#define N_EXP   16
#define SEQ     4096
#define NBATCH  4
#define NTOK    (NBATCH*SEQ)
#define DFFN    32
#define DTASK   64
#define NASSIGN (2*NTOK)

// ws layout (bytes)
#define WS_SUMS   0                      // double[8]  (per batch: sum, sumsq)
#define WS_RS     64                     // float[4]
#define WS_MU     80                     // float[4]
#define WS_GB     128                    // float[64]
#define WS_CNT    512                    // int[32]
#define WS_OFF    640                    // int[32]
#define WS_TOKREC 1024                   // float4[NTOK]   (256 KB)
#define WS_BUCKET (1024 + NTOK*16)       // int[32][NTOK]  (2 MB)
#define WS_H      (WS_BUCKET + 32*NTOK*4)// float[(NASSIGN+64)][32] (4 MB)

#define OUT_LB  (NTOK*D_MODEL)
#define OUT_IDX (NTOK*D_MODEL + 1)

__device__ __forceinline__ void atomAddF(float* p, float v) {
  unsafeAtomicAdd(p, v);   // hw global_atomic_add_f32 on gfx950
}
__device__ __forceinline__ float4 fma4(float s, float4 w, float4 a) {
  a.x = fmaf(s, w.x, a.x); a.y = fmaf(s, w.y, a.y);
  a.z = fmaf(s, w.z, a.z); a.w = fmaf(s, w.w, a.w);
  return a;
}
__device__ __forceinline__ float siluw(float v, float w) {
  return w * v / (1.f + __expf(-v));
}

// ---------------- stats: per-batch sum / sumsq over 4M elems ----------------
__global__ __launch_bounds__(256) void k_stats(const float* __restrict__ x,
                                               double* __restrict__ sums) {
  int b = blockIdx.y;
  const float4* xb = (const float4*)(x + (size_t)b * SEQ * D_MODEL);
  const int n4 = SEQ * D_MODEL / 4;
  double s = 0.0, ss = 0.0;
  for (int i = blockIdx.x * 256 + threadIdx.x; i < n4; i += gridDim.x * 256) {
    float4 v = xb[i];
    s  += (double)v.x + (double)v.y + (double)v.z + (double)v.w;
    ss += (double)v.x*v.x + (double)v.y*v.y + (double)v.z*v.z + (double)v.w*v.w;
  }
  __shared__ double r0[256], r1[256];
  r0[threadIdx.x] = s; r1[threadIdx.x] = ss;
  __syncthreads();
  for (int off = 128; off > 0; off >>= 1) {
    if (threadIdx.x < off) { r0[threadIdx.x] += r0[threadIdx.x+off]; r1[threadIdx.x] += r1[threadIdx.x+off]; }
    __syncthreads();
  }
  if (threadIdx.x == 0) { atomicAdd(&sums[2*b], r0[0]); atomicAdd(&sums[2*b+1], r1[0]); }
}

// ---------------- prep: mu/rs, Wg colsums, per-(b,e) gating offsets --------
__global__ __launch_bounds__(256) void k_prep(const double* __restrict__ sums,
    const int* __restrict__ task_id, const float* __restrict__ task_emb,
    const float* __restrict__ Wg, const float* __restrict__ bg,
    float* __restrict__ wsf) {
  __shared__ float smu[4], srs[4], sSe[16];
  __shared__ float red[16][16];
  int tid = threadIdx.x;
  if (tid < 4) {
    double n = (double)SEQ * (double)D_MODEL;
    double mu = sums[2*tid] / n;
    double var = sums[2*tid+1] / n - mu*mu;
    float rsv = (float)(1.0 / sqrt(var + 1e-5));
    smu[tid] = (float)mu; srs[tid] = rsv;
    wsf[WS_RS/4 + tid] = rsv; wsf[WS_MU/4 + tid] = (float)mu;
  }
  {
    int e = tid & 15, part = tid >> 4;
    float p = 0.f;
    for (int r = part*64; r < part*64 + 64; ++r) p += Wg[r*N_EXP + e];
    red[part][e] = p;
  }
  __syncthreads();
  if (tid < 16) {
    float t = 0.f;
    for (int i = 0; i < 16; ++i) t += red[i][tid];
    sSe[tid] = t;
  }
  __syncthreads();
  if (tid < 64) {
    int b = tid >> 4, e = tid & 15;
    int tk = task_id[b];
    float off = 0.f;
    for (int j = 0; j < DTASK; ++j)
      off += task_emb[tk*DTASK + j] * Wg[(D_MODEL + j)*N_EXP + e];
    wsf[WS_GB/4 + tid] = bg[e] + off - srs[b]*smu[b]*sSe[e];
  }
}

// ---------------- gating: logits, top-2, softmax, bucket scatter -----------
__global__ __launch_bounds__(256) void k_gating(const float* __restrict__ x,
    const float* __restrict__ Wg, const float* __restrict__ wsf,
    float* __restrict__ out, float4* __restrict__ tokrec,
    int* __restrict__ cnt, int* __restrict__ bucket) {
  __shared__ float wgT[N_EXP][D_MODEL + 1];
  __shared__ float lg[4][4][16];
  int tid = threadIdx.x;
  for (int i = tid; i < D_MODEL*N_EXP/4; i += 256) {
    float4 v = ((const float4*)Wg)[i];
    int d = i >> 2, e0 = (i & 3) << 2;
    wgT[e0+0][d] = v.x; wgT[e0+1][d] = v.y; wgT[e0+2][d] = v.z; wgT[e0+3][d] = v.w;
  }
  __syncthreads();
  int wave = tid >> 6, lane = tid & 63;
  int blk0 = blockIdx.x * 64;
  int b = blk0 >> 12;
  float rsb = wsf[WS_RS/4 + b];
  for (int it = 0; it < 4; ++it) {
    int tbase = blk0 + wave*16 + it*4;
    float xr[4][16];
    #pragma unroll
    for (int tt = 0; tt < 4; ++tt) {
      const float* xp = x + (size_t)(tbase + tt)*D_MODEL + lane;
      #pragma unroll
      for (int j = 0; j < 16; ++j) xr[tt][j] = xp[j*64];
    }
    float v[64];
    #pragma unroll
    for (int i = 0; i < 64; ++i) v[i] = 0.f;
    #pragma unroll
    for (int j = 0; j < 16; ++j) {
      int d = lane + 64*j;
      #pragma unroll
      for (int e = 0; e < 16; ++e) {
        float w = wgT[e][d];
        #pragma unroll
        for (int tt = 0; tt < 4; ++tt) v[tt*16 + e] = fmaf(xr[tt][j], w, v[tt*16 + e]);
      }
    }
    #pragma unroll
    for (int m = 32; m >= 1; m >>= 1) {
      #pragma unroll
      for (int j2 = 0; j2 < m; ++j2) {
        float lo = v[j2], hi = v[j2 + m];
        bool up = (lane & m) != 0;
        float mine = up ? hi : lo;
        float theirs = up ? lo : hi;
        v[j2] = mine + __shfl_xor(theirs, m, 64);
      }
    }
    int e = lane & 15, tt = lane >> 4;
    float logit = fmaf(rsb, v[0], wsf[WS_GB/4 + b*16 + e]);
    lg[wave][tt][e] = logit;
    __syncthreads();
    if ((lane & 15) == 0) {
      int token = tbase + tt;
      float v0 = -1e30f, v1 = -1e30f; int i0 = 0, i1 = 0;
      #pragma unroll
      for (int ee = 0; ee < 16; ++ee) {
        float L = lg[wave][tt][ee];
        if (L > v0)      { v1 = v0; i1 = i0; v0 = L; i0 = ee; }
        else if (L > v1) { v1 = L; i1 = ee; }
      }
      float ex = __expf(v1 - v0);
      float p0 = 1.f / (1.f + ex);
      float p1 = ex * p0;
      out[OUT_IDX + token*2 + 0] = (float)i0;
      out[OUT_IDX + token*2 + 1] = (float)i1;
      tokrec[token] = make_float4(__int_as_float(i0), __int_as_float(i1), p0, p1);
      int pos0 = atomicAdd(&cnt[i0], 1);
      bucket[i0*NTOK + pos0] = token;
      int pos1 = atomicAdd(&cnt[16 + i1], 1);
      bucket[16*NTOK + i1*NTOK + pos1] = token;
    }
    __syncthreads();
  }
}

// ---------------- prefix offsets + lb loss ---------------------------------
__global__ void k_off_lb(const int* __restrict__ cnt, int* __restrict__ off,
                         float* __restrict__ out) {
  if (threadIdx.x == 0 && blockIdx.x == 0) {
    int s = 0;
    for (int ke = 0; ke < 32; ++ke) { off[ke] = s; s += cnt[ke]; }
    float u[16], tot = 0.f;
    for (int e = 0; e < 16; ++e) { u[e] = (float)(cnt[e] + cnt[16+e]); tot += u[e]; }
    float mean = tot / 16.f, var = 0.f;
    for (int e = 0; e < 16; ++e) { float d = u[e] - mean; var += d*d; }
    var /= 15.f;
    float m = mean + 1e-6f;
    out[OUT_LB] = var / (m*m);
  }
}

// ---------------- phase 1: h = x @ W1[e] + b1[e], packed into ws -----------
#define HT 64
#define BK 64
__global__ __launch_bounds__(256) void k_h(const float* __restrict__ x,
    const float* __restrict__ W1, const float* __restrict__ b1,
    const int* __restrict__ cnt, const int* __restrict__ off,
    const int* __restrict__ bucket, float* __restrict__ h) {
  int ke = blockIdx.y, e = ke & 15;
  int cntE = cnt[ke];
  int r0 = blockIdx.x * HT;
  if (r0 >= cntE) return;
  int R = min(HT, cntE - r0);
  __shared__ int toks[HT];
  __shared__ float xs[HT][BK + 4];
  __shared__ float w1s[BK * DFFN];
  int tid = threadIdx.x;
  if (tid < HT) toks[tid] = bucket[ke * NTOK + ((tid < R) ? (r0 + tid) : r0)];
  __syncthreads();
  int lr = tid >> 2, lq = tid & 3;
  int a2 = tid >> 3, fg = tid & 7;
  const float* W1e = W1 + (size_t)e * D_MODEL * DFFN;
  const float* xrow = x + (size_t)toks[lr] * D_MODEL + lq * 16;
  float4 xa[4], wa[2];
  // prologue: chunk 0 loads
  xa[0] = *(const float4*)(xrow + 0);
  xa[1] = *(const float4*)(xrow + 4);
  xa[2] = *(const float4*)(xrow + 8);
  xa[3] = *(const float4*)(xrow + 12);
  {
    const float4* wg = (const float4*)W1e;
    wa[0] = wg[tid]; wa[1] = wg[tid + 256];
  }
  float4 acc0 = make_float4(0,0,0,0), acc1 = make_float4(0,0,0,0);
  #pragma unroll 1
  for (int c = 0; c < D_MODEL / BK; ++c) {
    if (c) __syncthreads();
    *(float4*)&xs[lr][lq*16 + 0]  = xa[0];
    *(float4*)&xs[lr][lq*16 + 4]  = xa[1];
    *(float4*)&xs[lr][lq*16 + 8]  = xa[2];
    *(float4*)&xs[lr][lq*16 + 12] = xa[3];
    ((float4*)w1s)[tid]       = wa[0];
    ((float4*)w1s)[tid + 256] = wa[1];
    __syncthreads();
    if (c + 1 < D_MODEL / BK) {
      const float* xn = xrow + (c + 1) * BK;
      xa[0] = *(const float4*)(xn + 0);
      xa[1] = *(const float4*)(xn + 4);
      xa[2] = *(const float4*)(xn + 8);
      xa[3] = *(const float4*)(xn + 12);
      const float4* wg = (const float4*)(W1e + (c + 1) * BK * DFFN);
      wa[0] = wg[tid]; wa[1] = wg[tid + 256];
    }
    #pragma unroll
    for (int kk = 0; kk < BK; kk += 4) {
      float4 xv0 = *(const float4*)&xs[2*a2][kk];
      float4 xv1 = *(const float4*)&xs[2*a2+1][kk];
      const float* wb = &w1s[kk * DFFN + 4 * fg];
      float4 w0  = *(const float4*)(wb);
      float4 w1r = *(const float4*)(wb + DFFN);
      float4 w2r = *(const float4*)(wb + 2*DFFN);
      float4 w3r = *(const float4*)(wb + 3*DFFN);
      acc0 = fma4(xv0.x, w0,  acc0); acc1 = fma4(xv1.x, w0,  acc1);
      acc0 = fma4(xv0.y, w1r, acc0); acc1 = fma4(xv1.y, w1r, acc1);
      acc0 = fma4(xv0.z, w2r, acc0); acc1 = fma4(xv1.z, w2r, acc1);
      acc0 = fma4(xv0.w, w3r, acc0); acc1 = fma4(xv1.w, w3r, acc1);
    }
  }
  float4 b1v = *(const float4*)(b1 + e * DFFN + 4 * fg);
  acc0.x += b1v.x; acc0.y += b1v.y; acc0.z += b1v.z; acc0.w += b1v.w;
  acc1.x += b1v.x; acc1.y += b1v.y; acc1.z += b1v.z; acc1.w += b1v.w;
  int base = off[ke] + r0;
  if (2*a2 < R)     *(float4*)&h[(size_t)(base + 2*a2)     * DFFN + 4*fg] = acc0;
  if (2*a2 + 1 < R) *(float4*)&h[(size_t)(base + 2*a2 + 1) * DFFN + 4*fg] = acc1;
}

// ---------------- phase 2: out = silu(h)*w @ W2 (+ biases in MODE 0) -------
#define OT 32
#define DCH 256
template<int MODE>
__global__ __launch_bounds__(256) void k_o(const float* __restrict__ h,
    const float* __restrict__ W2, const float* __restrict__ b2,
    const float4* __restrict__ tokrec, const int* __restrict__ cnt,
    const int* __restrict__ off, const int* __restrict__ bucket,
    float* __restrict__ out) {
  int e = blockIdx.y, ke = MODE * 16 + e;
  int cntE = cnt[ke];
  int r0 = blockIdx.x * OT;
  if (r0 >= cntE) return;
  int R = min(OT, cntE - r0);
  __shared__ float w2s[DFFN][DCH];
  __shared__ int toks[OT], eo[OT];
  __shared__ float wsl[OT], wot[OT];
  int tid = threadIdx.x;
  if (tid < OT) {
    int tok = bucket[ke * NTOK + ((tid < R) ? (r0 + tid) : r0)];
    toks[tid] = tok;
    float4 rec = tokrec[tok];
    if (MODE == 0) { wsl[tid] = rec.z; wot[tid] = rec.w; eo[tid] = __float_as_int(rec.y); }
    else           { wsl[tid] = rec.w; }
  }
  __syncthreads();
  int t2 = tid >> 4, dg = tid & 15;
  int ta = 2 * t2, tb = ta + 1;
  int tokA = toks[ta], tokB = toks[tb];
  float wA = wsl[ta], wB = wsl[tb];
  float hwA[DFFN], hwB[DFFN];
  {
    int base = off[ke] + r0;
    const float4* hA = (const float4*)(h + (size_t)(base + ta) * DFFN);
    const float4* hB = (const float4*)(h + (size_t)(base + tb) * DFFN);
    #pragma unroll
    for (int q = 0; q < 8; ++q) {
      float4 a = hA[q], b = hB[q];
      hwA[4*q+0] = siluw(a.x, wA); hwA[4*q+1] = siluw(a.y, wA);
      hwA[4*q+2] = siluw(a.z, wA); hwA[4*q+3] = siluw(a.w, wA);
      hwB[4*q+0] = siluw(b.x, wB); hwB[4*q+1] = siluw(b.y, wB);
      hwB[4*q+2] = siluw(b.z, wB); hwB[4*q+3] = siluw(b.w, wB);
    }
  }
  const float* W2e = W2 + (size_t)e * DFFN * D_MODEL;
  float4 st[8];
  #pragma unroll
  for (int i = 0; i < 8; ++i) {
    int idx = tid + i * 256;
    st[i] = *(const float4*)(W2e + (size_t)(idx >> 6) * D_MODEL + ((idx & 63) << 2));
  }
  #pragma unroll 1
  for (int dc = 0; dc < D_MODEL / DCH; ++dc) {
    if (dc) __syncthreads();
    #pragma unroll
    for (int i = 0; i < 8; ++i) {
      int idx = tid + i * 256;
      *(float4*)&w2s[idx >> 6][(idx & 63) << 2] = st[i];
    }
    __syncthreads();
    if (dc + 1 < D_MODEL / DCH) {
      #pragma unroll
      for (int i = 0; i < 8; ++i) {
        int idx = tid + i * 256;
        st[i] = *(const float4*)(W2e + (size_t)(idx >> 6) * D_MODEL
                                 + (dc + 1) * DCH + ((idx & 63) << 2));
      }
    }
    int d0 = dg * 4;
    float4 aA[4], aB[4];
    if (MODE == 0) {
      const float* bsE = b2 + (size_t)e * D_MODEL + dc * DCH + d0;
      const float* boA = b2 + (size_t)eo[ta] * D_MODEL + dc * DCH + d0;
      const float* boB = b2 + (size_t)eo[tb] * D_MODEL + dc * DCH + d0;
      float woA = wot[ta], woB = wot[tb];
      #pragma unroll
      for (int j = 0; j < 4; ++j) {
        float4 bs = *(const float4*)(bsE + 64 * j);
        float4 bA = *(const float4*)(boA + 64 * j);
        float4 bB = *(const float4*)(boB + 64 * j);
        aA[j] = make_float4(wA*bs.x + woA*bA.x, wA*bs.y + woA*bA.y,
                            wA*bs.z + woA*bA.z, wA*bs.w + woA*bA.w);
        aB[j] = make_float4(wB*bs.x + woB*bB.x, wB*bs.y + woB*bB.y,
                            wB*bs.z + woB*bB.z, wB*bs.w + woB*bB.w);
      }
    } else {
      #pragma unroll
      for (int j = 0; j < 4; ++j) {
        aA[j] = make_float4(0.f, 0.f, 0.f, 0.f);
        aB[j] = make_float4(0.f, 0.f, 0.f, 0.f);
      }
    }
    #pragma unroll
    for (int f = 0; f < DFFN; ++f) {
      const float* wb = &w2s[f][d0];
      float4 w0  = *(const float4*)(wb);
      float4 w1r = *(const float4*)(wb + 64);
      float4 w2r = *(const float4*)(wb + 128);
      float4 w3r = *(const float4*)(wb + 192);
      float ha = hwA[f], hb = hwB[f];
      aA[0] = fma4(ha, w0,  aA[0]); aA[1] = fma4(ha, w1r, aA[1]);
      aA[2] = fma4(ha, w2r, aA[2]); aA[3] = fma4(ha, w3r, aA[3]);
      aB[0] = fma4(hb, w0,  aB[0]); aB[1] = fma4(hb, w1r, aB[1]);
      aB[2] = fma4(hb, w2r, aB[2]); aB[3] = fma4(hb, w3r, aB[3]);
    }
    float* oA = out + (size_t)tokA * D_MODEL + dc * DCH + d0;
    float* oB = out + (size_t)tokB * D_MODEL + dc * DCH + d0;
    if (MODE == 0) {
      if (ta < R) {
        #pragma unroll
        for (int j = 0; j < 4; ++j) *(float4*)(oA + 64 * j) = aA[j];
      }
      if (tb < R) {
        #pragma unroll
        for (int j = 0; j < 4; ++j) *(float4*)(oB + 64 * j) = aB[j];
      }
    } else {
      if (ta < R) {
        #pragma unroll
        for (int j = 0; j < 4; ++j) {
          float* p = oA + 64 * j;
          atomAddF(p+0, aA[j].x); atomAddF(p+1, aA[j].y);
          atomAddF(p+2, aA[j].z); atomAddF(p+3, aA[j].w);
        }
      }
      if (tb < R) {
        #pragma unroll
        for (int j = 0; j < 4; ++j) {
          float* p = oB + 64 * j;
          atomAddF(p+0, aB[j].x); atomAddF(p+1, aB[j].y);
          atomAddF(p+2, aB[j].z); atomAddF(p+3, aB[j].w);
        }
      }
    }
  }
}

extern "C" void kernel_launch(void* const* d_in, const int* in_sizes, int n_in,
                              void* d_out, int out_size, void* d_ws, size_t ws_size,
                              hipStream_t stream) {
  const float* x        = (const float*)d_in[0];
  const int*   task_id  = (const int*)  d_in[1];
  const float* task_emb = (const float*)d_in[2];
  const float* Wg       = (const float*)d_in[3];
  const float* bg       = (const float*)d_in[4];
  const float* W1       = (const float*)d_in[5];
  const float* b1       = (const float*)d_in[6];
  const float* W2       = (const float*)d_in[7];
  const float* b2       = (const float*)d_in[8];
  float* out = (float*)d_out;
  char* ws = (char*)d_ws;
  double* sums   = (double*)(ws + WS_SUMS);
  float*  wsf    = (float*) ws;
  float4* tokrec = (float4*)(ws + WS_TOKREC);
  int*    cnt    = (int*)   (ws + WS_CNT);
  int*    off    = (int*)   (ws + WS_OFF);
  int*    bucket = (int*)   (ws + WS_BUCKET);
  float*  h      = (float*) (ws + WS_H);

  hipMemsetAsync(ws, 0, 1024, stream);
  k_stats<<<dim3(128, 4), 256, 0, stream>>>(x, sums);
  k_prep<<<1, 256, 0, stream>>>(sums, task_id, task_emb, Wg, bg, wsf);
  k_gating<<<NTOK/64, 256, 0, stream>>>(x, Wg, wsf, out, tokrec, cnt, bucket);
  k_off_lb<<<1, 64, 0, stream>>>(cnt, off, out);
  k_h<<<dim3(96, 32), 256, 0, stream>>>(x, W1, b1, cnt, off, bucket, h);
  k_o<0><<<dim3(192, 16), 256, 0, stream>>>(h, W2, b2, tokrec, cnt, off, bucket, out);
  k_o<1><<<dim3(192, 16), 256, 0, stream>>>(h, W2, b2, tokrec, cnt, off, bucket, out);
}